// Round 1
// baseline (3963.126 us; speedup 1.0000x reference)
//
#include <hip/hip_runtime.h>
#include <stdint.h>

typedef _Float16 f16;
typedef _Float16 f16x4 __attribute__((ext_vector_type(4)));
typedef _Float16 f16x8 __attribute__((ext_vector_type(8)));
typedef float f32x4 __attribute__((ext_vector_type(4)));

#define SEQ 512
#define NB  200
#define HD  256
#define GD  768
#define BW  16
#define NBLK 13   // ceil(200/16)

__device__ __forceinline__ f32x4 mfma16(f16x8 a, f16x8 b, f32x4 c){
  return __builtin_amdgcn_mfma_f32_16x16x32_f16(a, b, c, 0, 0, 0);
}

// ---------------- fp32 -> fp16 convert ----------------
__global__ void cvt_f32_f16(const float* __restrict__ src, f16* __restrict__ dst, int n4){
  int i = blockIdx.x * blockDim.x + threadIdx.x;
  int stride = gridDim.x * blockDim.x;
  for (; i < n4; i += stride){
    float4 v = ((const float4*)src)[i];
    f16x4 o = { (f16)v.x, (f16)v.y, (f16)v.z, (f16)v.w };
    ((f16x4*)dst)[i] = o;
  }
}

// ---------------- GEMM: C[m][n] = sum_k A[m][k]*B[n][k] (both K-major) -------
// MODE 0: fp16 out + bias[col] added. grid (M/128, N/128, 1), klen == K
// MODE 1: fp32 partials out[(z*512+row)*N+col].  grid (M/128, N/128, splits)
template<int MODE>
__global__ __launch_bounds__(256, 2)
void gemm_bt(const f16* __restrict__ A, const f16* __restrict__ B,
             f16* __restrict__ Cb, float* __restrict__ Cf,
             const float* __restrict__ bias, int K, int N, int klen)
{
  const int l  = threadIdx.x & 63;
  const int w  = threadIdx.x >> 6;
  const int lr = l & 15, lg = l >> 4;
  const int Mb = blockIdx.x * 128 + (w >> 1) * 64;
  const int Nb = blockIdx.y * 128 + (w & 1) * 64;
  const int kb = blockIdx.z * klen;

  const f16* Ap = A + (size_t)(Mb + lr) * K + kb + lg * 8;
  const f16* Bp = B + (size_t)(Nb + lr) * K + kb + lg * 8;

  f32x4 acc[4][4];
  #pragma unroll
  for (int i = 0; i < 4; ++i)
    #pragma unroll
    for (int j = 0; j < 4; ++j)
      acc[i][j] = (f32x4){0.f, 0.f, 0.f, 0.f};

  for (int k = 0; k < klen; k += 32){
    f16x8 af[4], bfr[4];
    #pragma unroll
    for (int i = 0; i < 4; ++i){
      af[i]  = *(const f16x8*)(Ap + (size_t)i * 16 * K + k);
      bfr[i] = *(const f16x8*)(Bp + (size_t)i * 16 * K + k);
    }
    #pragma unroll
    for (int i = 0; i < 4; ++i)
      #pragma unroll
      for (int j = 0; j < 4; ++j)
        acc[i][j] = mfma16(af[i], bfr[j], acc[i][j]);
  }

  if (MODE == 0){
    float bv[4];
    #pragma unroll
    for (int j = 0; j < 4; ++j) bv[j] = bias[Nb + j*16 + lr];
    #pragma unroll
    for (int i = 0; i < 4; ++i)
      #pragma unroll
      for (int j = 0; j < 4; ++j)
        #pragma unroll
        for (int r = 0; r < 4; ++r){
          int row = Mb + i*16 + lg*4 + r;
          int col = Nb + j*16 + lr;
          Cb[(size_t)row * N + col] = (f16)(acc[i][j][r] + bv[j]);
        }
  } else {
    #pragma unroll
    for (int i = 0; i < 4; ++i)
      #pragma unroll
      for (int j = 0; j < 4; ++j)
        #pragma unroll
        for (int r = 0; r < 4; ++r){
          int row = Mb + i*16 + lg*4 + r;
          int col = Nb + j*16 + lr;
          Cf[((size_t)blockIdx.z * 512 + row) * N + col] = acc[i][j][r];
        }
  }
}

// ---------------- persistent GRU layer: 13 blocks x 16 batch rows ------------
// Wave w owns hidden slice j in [32w, 32w+32): gate rows {j, 256+j, 512+j}.
// w_hh fragments register-resident (192 VGPR/lane). h fp32 in regs, fp16 in
// XOR-swizzled LDS for next step's B-fragments.
__global__ __launch_bounds__(512, 2)
void gru_layer(const f16* __restrict__ whh, const float* __restrict__ bhh,
               const f16* __restrict__ gi, f16* __restrict__ hs)
{
  __shared__ f16   hlds[BW * HD];   // [b][k], byte ^= (b&7)<<4
  __shared__ float blds[GD];
  const int tid = threadIdx.x;
  const int w = tid >> 6, l = tid & 63;
  const int lr = l & 15, lg = l >> 4;
  const int jw = w * 32;
  const int b0 = blockIdx.x * BW;
  const int realB = (NB - b0 < BW) ? (NB - b0) : BW;
  const int bcol = lr;
  const int browg = (b0 + bcol < NB) ? (b0 + bcol) : (NB - 1);
  const bool bval = bcol < realB;

  for (int i = tid; i < BW * HD; i += 512) hlds[i] = (f16)0.f;
  for (int i = tid; i < GD; i += 512) blds[i] = bhh[i];

  // A-fragments: tile (q,t2) covers gate rows q*256 + jw + t2*16 + [0,16)
  f16x8 wA[6][8];
  #pragma unroll
  for (int q = 0; q < 3; ++q)
    #pragma unroll
    for (int t2 = 0; t2 < 2; ++t2)
      #pragma unroll
      for (int kk = 0; kk < 8; ++kk)
        wA[q*2+t2][kk] = *(const f16x8*)(whh + (size_t)(q*256 + jw + t2*16 + lr) * HD + kk*32 + lg*8);

  float hreg[2][4] = {{0.f,0.f,0.f,0.f},{0.f,0.f,0.f,0.f}};
  __syncthreads();

  const int wbyte = bcol * 512;
  const int swz = (bcol & 7) << 4;

  for (int t = 0; t < SEQ; ++t){
    // init acc with b_hh (rows match D-layout: row = lg*4 + r)
    f32x4 acc[3][2];
    #pragma unroll
    for (int q = 0; q < 3; ++q)
      #pragma unroll
      for (int t2 = 0; t2 < 2; ++t2)
        acc[q][t2] = *(const f32x4*)&blds[q*256 + jw + t2*16 + lg*4];

    // gi loads (independent of LDS; issued early)
    const f16* gp = gi + (size_t)(t * NB + browg) * GD + jw + lg * 4;
    f16x4 gr0 = *(const f16x4*)(gp);
    f16x4 gr1 = *(const f16x4*)(gp + 16);
    f16x4 gz0 = *(const f16x4*)(gp + 256);
    f16x4 gz1 = *(const f16x4*)(gp + 272);
    f16x4 gn0 = *(const f16x4*)(gp + 512);
    f16x4 gn1 = *(const f16x4*)(gp + 528);

    // gh = w_hh @ h : B-frag = h[bcol][k..k+7] from swizzled LDS
    #pragma unroll
    for (int kk = 0; kk < 8; ++kk){
      int off = (wbyte + kk*64 + lg*16) ^ swz;
      f16x8 hf = *(const f16x8*)((const char*)hlds + off);
      #pragma unroll
      for (int q = 0; q < 3; ++q)
        #pragma unroll
        for (int t2 = 0; t2 < 2; ++t2)
          acc[q][t2] = mfma16(wA[q*2+t2][kk], hf, acc[q][t2]);
    }
    __syncthreads();   // all B-frag reads done before overwrite

    #pragma unroll
    for (int t2 = 0; t2 < 2; ++t2){
      float ir4[4], iz4[4], in4[4];
      #pragma unroll
      for (int r = 0; r < 4; ++r){
        ir4[r] = (float)(t2 ? gr1[r] : gr0[r]);
        iz4[r] = (float)(t2 ? gz1[r] : gz0[r]);
        in4[r] = (float)(t2 ? gn1[r] : gn0[r]);
      }
      f16x4 hv;
      #pragma unroll
      for (int r = 0; r < 4; ++r){
        float hr = acc[0][t2][r], hz = acc[1][t2][r], hn = acc[2][t2][r];
        float rg = 1.f / (1.f + __expf(-(ir4[r] + hr)));
        float zg = 1.f / (1.f + __expf(-(iz4[r] + hz)));
        float a  = in4[r] + rg * hn;
        float ng = 2.f / (1.f + __expf(-2.f * a)) - 1.f;   // tanh, inf-safe
        float h  = (1.f - zg) * ng + zg * hreg[t2][r];
        hreg[t2][r] = h;
        hv[r] = (f16)h;
      }
      int jb = (jw + t2*16 + lg*4) * 2;
      *(f16x4*)((char*)hlds + ((wbyte + jb) ^ swz)) = hv;
      if (bval)
        *(f16x4*)(hs + (size_t)(t * NB + b0 + bcol) * HD + jw + t2*16 + lg*4) = hv;
    }
    __syncthreads();   // hlds ready for next step
  }
}

// ---------------- LayerNorm(hidden) + ReLU, in place on fp16 [rows][256] -----
__global__ __launch_bounds__(256)
void ln_relu(f16* __restrict__ hs, const float* __restrict__ lnw,
             const float* __restrict__ lnb)
{
  __shared__ float lds[8];
  const int tid = threadIdx.x;
  const int w = tid >> 6;
  const float gw = lnw[tid], gb = lnb[tid];
  for (int row = blockIdx.x; row < SEQ * NB; row += gridDim.x){
    f16* p = hs + (size_t)row * HD;
    float v = (float)p[tid];
    float s = v, q = v * v;
    #pragma unroll
    for (int off = 32; off; off >>= 1){
      s += __shfl_down(s, off);
      q += __shfl_down(q, off);
    }
    if ((tid & 63) == 0){ lds[w] = s; lds[4 + w] = q; }
    __syncthreads();
    float S = lds[0] + lds[1] + lds[2] + lds[3];
    float Q = lds[4] + lds[5] + lds[6] + lds[7];
    float mu = S * (1.f / HD);
    float var = Q * (1.f / HD) - mu * mu;
    float y = (v - mu) * rsqrtf(var + 1e-5f) * gw + gb;
    p[tid] = (f16)fmaxf(y, 0.f);
    __syncthreads();
  }
}

// ---------------- BatchNorm over axis0 (batch stats) + ReLU ------------------
// partials: [8][o=512][s=512]; one block per column o, thread = s.
__global__ __launch_bounds__(512)
void bn_relu(const float* __restrict__ part, const float* __restrict__ g,
             const float* __restrict__ b, float* __restrict__ z)
{
  __shared__ float lds[16];
  const int o = blockIdx.x, s = threadIdx.x, w = s >> 6;
  float y = 0.f;
  #pragma unroll
  for (int p = 0; p < 8; ++p) y += part[((size_t)p * 512 + o) * 512 + s];
  float su = y, q = y * y;
  #pragma unroll
  for (int off = 32; off; off >>= 1){
    su += __shfl_down(su, off);
    q  += __shfl_down(q, off);
  }
  if ((s & 63) == 0){ lds[w] = su; lds[8 + w] = q; }
  __syncthreads();
  float S = 0.f, Q = 0.f;
  #pragma unroll
  for (int i = 0; i < 8; ++i){ S += lds[i]; Q += lds[8 + i]; }
  float mu = S * (1.f / 512.f);
  float var = Q * (1.f / 512.f) - mu * mu;
  float zz = fmaxf((y - mu) * rsqrtf(var + 1e-5f) * g[o] + b[o], 0.f);
  z[(size_t)o * 512 + s] = zz;   // stored transposed [o][s]
}

// ---------------- fc3: out[s][c] = sum_o z[o][s]*w[c][o] + b[c] --------------
__global__ __launch_bounds__(256)
void fc3_k(const float* __restrict__ z, const float* __restrict__ w,
           const float* __restrict__ b, float* __restrict__ out)
{
  __shared__ float lds[12];
  const int s = blockIdx.x, tid = threadIdx.x, wv = tid >> 6;
  float a0 = 0.f, a1 = 0.f, a2 = 0.f;
  for (int o = tid; o < 512; o += 256){
    float zz = z[(size_t)o * 512 + s];
    a0 += zz * w[o];
    a1 += zz * w[512 + o];
    a2 += zz * w[1024 + o];
  }
  #pragma unroll
  for (int off = 32; off; off >>= 1){
    a0 += __shfl_down(a0, off);
    a1 += __shfl_down(a1, off);
    a2 += __shfl_down(a2, off);
  }
  if ((tid & 63) == 0){ lds[wv] = a0; lds[4 + wv] = a1; lds[8 + wv] = a2; }
  __syncthreads();
  if (tid == 0){
    out[s*3 + 0] = lds[0] + lds[1] + lds[2]  + lds[3]  + b[0];
    out[s*3 + 1] = lds[4] + lds[5] + lds[6]  + lds[7]  + b[1];
    out[s*3 + 2] = lds[8] + lds[9] + lds[10] + lds[11] + b[2];
  }
}

extern "C" void kernel_launch(void* const* d_in, const int* in_sizes, int n_in,
                              void* d_out, int out_size, void* d_ws, size_t ws_size,
                              hipStream_t stream)
{
  (void)in_sizes; (void)n_in; (void)out_size; (void)ws_size;
  const float* x    = (const float*)d_in[0];
  const float* wih0 = (const float*)d_in[1];
  const float* whh0 = (const float*)d_in[2];
  const float* bih0 = (const float*)d_in[3];
  const float* bhh0 = (const float*)d_in[4];
  const float* wih1 = (const float*)d_in[5];
  const float* whh1 = (const float*)d_in[6];
  const float* bih1 = (const float*)d_in[7];
  const float* bhh1 = (const float*)d_in[8];
  const float* lnw  = (const float*)d_in[9];
  const float* lnb  = (const float*)d_in[10];
  const float* fc2w = (const float*)d_in[11];
  // d_in[12] = fc2_b: skipped — BN mean-centering cancels a constant column
  // bias exactly (y+c - mean(y+c) == y - mean(y)).
  const float* bng  = (const float*)d_in[13];
  const float* bnb  = (const float*)d_in[14];
  const float* fc3w = (const float*)d_in[15];
  const float* fc3b = (const float*)d_in[16];
  float* out = (float*)d_out;

  char* ws = (char*)d_ws;
  size_t off = 0;
  auto alloc = [&](size_t bytes) -> void* {
    void* p = ws + off; off += (bytes + 255) & ~(size_t)255; return p;
  };
  f16* X16    = (f16*)alloc((size_t)SEQ*NB*64*2);     // 13.1 MB
  f16* WI0    = (f16*)alloc((size_t)768*64*2);
  f16* WH0    = (f16*)alloc((size_t)768*256*2);
  f16* WI1    = (f16*)alloc((size_t)768*256*2);
  f16* WH1    = (f16*)alloc((size_t)768*256*2);
  f16* FC2W   = (f16*)alloc((size_t)512*51200*2);     // 52.4 MB
  f16* GI     = (f16*)alloc((size_t)SEQ*NB*768*2);    // 157.3 MB (reused L0/L1)
  f16* HS0    = (f16*)alloc((size_t)SEQ*NB*256*2);    // 52.4 MB
  f16* HS1    = (f16*)alloc((size_t)SEQ*NB*256*2);    // 52.4 MB
  float* PART = (float*)alloc((size_t)8*512*512*4);   // 8.4 MB
  float* Z    = (float*)alloc((size_t)512*512*4);     // 1 MB  (total ~323 MB)

  cvt_f32_f16<<<2048,256,0,stream>>>(x,    X16,  SEQ*NB*64/4);
  cvt_f32_f16<<<64,  256,0,stream>>>(wih0, WI0,  768*64/4);
  cvt_f32_f16<<<192, 256,0,stream>>>(whh0, WH0,  768*256/4);
  cvt_f32_f16<<<192, 256,0,stream>>>(wih1, WI1,  768*256/4);
  cvt_f32_f16<<<192, 256,0,stream>>>(whh1, WH1,  768*256/4);
  cvt_f32_f16<<<4096,256,0,stream>>>(fc2w, FC2W, 512*51200/4);

  dim3 g0(800, 6, 1);
  // gi0 = x @ w_ih0^T + b_ih0
  gemm_bt<0><<<g0, 256, 0, stream>>>(X16, WI0, GI, nullptr, bih0, 64, GD, 64);
  gru_layer<<<NBLK, 512, 0, stream>>>(WH0, bhh0, GI, HS0);
  // gi1 = hs0 @ w_ih1^T + b_ih1
  gemm_bt<0><<<g0, 256, 0, stream>>>(HS0, WI1, GI, nullptr, bih1, 256, GD, 256);
  gru_layer<<<NBLK, 512, 0, stream>>>(WH1, bhh1, GI, HS1);
  // LayerNorm + ReLU in place -> hflat (fp16, layout already (512, 51200))
  ln_relu<<<2048, 256, 0, stream>>>(HS1, lnw, lnb);
  // y^T partials: C[o][s] = fc2_w[o,:] . hflat[s,:], split-K=8
  dim3 g2(4, 4, 8);
  gemm_bt<1><<<g2, 256, 0, stream>>>(FC2W, HS1, nullptr, PART, nullptr, 51200, 512, 6400);
  bn_relu<<<512, 512, 0, stream>>>(PART, bng, bnb, Z);
  fc3_k<<<512, 256, 0, stream>>>(Z, fc3w, fc3b, out);
}

// Round 2
// 2894.557 us; speedup vs baseline: 1.3692x; 1.3692x over previous
//
#include <hip/hip_runtime.h>
#include <stdint.h>

typedef _Float16 f16;
typedef _Float16 f16x4 __attribute__((ext_vector_type(4)));
typedef _Float16 f16x8 __attribute__((ext_vector_type(8)));
typedef float f32x4 __attribute__((ext_vector_type(4)));

#define SEQ 512
#define NB  200
#define HD  256
#define GD  768
#define BW  16
#define NBLK 13           // ceil(200/16)
#define NBP 208           // padded batch for GI layout
#define GI_TSTRIDE (3*32*NBP*8)   // halves per timestep = 159744
#define LOG2E 1.44269504f

__device__ __forceinline__ f32x4 mfma16(f16x8 a, f16x8 b, f32x4 c){
  return __builtin_amdgcn_mfma_f32_16x16x32_f16(a, b, c, 0, 0, 0);
}

// ---------------- fp32 -> fp16 convert ----------------
__global__ void cvt_f32_f16(const float* __restrict__ src, f16* __restrict__ dst, int n4){
  int i = blockIdx.x * blockDim.x + threadIdx.x;
  int stride = gridDim.x * blockDim.x;
  for (; i < n4; i += stride){
    float4 v = ((const float4*)src)[i];
    f16x4 o = { (f16)v.x, (f16)v.y, (f16)v.z, (f16)v.w };
    ((f16x4*)dst)[i] = o;
  }
}

// ---------------- GEMM: C[m][n] = sum_k A[m][k]*B[n][k] (both K-major) -------
// MODE 0: fp16 out into PERMUTED GI layout, bias1[col] (+bias2[col] for col<512).
//         Rows are (t*200+b). GI half index:
//         ((((t*3+q)*32 + ww*4+lg2)*208 + b)*8 + tt2*4+rr,  col g = q*256+ww*32+tt2*16+lg2*4+rr
// MODE 1: fp32 partials out[(z*512+row)*N+col].  grid (M/128, N/128, splits)
template<int MODE>
__global__ __launch_bounds__(256, 2)
void gemm_bt(const f16* __restrict__ A, const f16* __restrict__ B,
             f16* __restrict__ Cb, float* __restrict__ Cf,
             const float* __restrict__ bias1, const float* __restrict__ bias2,
             int K, int N, int klen)
{
  const int l  = threadIdx.x & 63;
  const int w  = threadIdx.x >> 6;
  const int lr = l & 15, lg = l >> 4;
  const int Mb = blockIdx.x * 128 + (w >> 1) * 64;
  const int Nb = blockIdx.y * 128 + (w & 1) * 64;
  const int kb = blockIdx.z * klen;

  const f16* Ap = A + (size_t)(Mb + lr) * K + kb + lg * 8;
  const f16* Bp = B + (size_t)(Nb + lr) * K + kb + lg * 8;

  f32x4 acc[4][4];
  #pragma unroll
  for (int i = 0; i < 4; ++i)
    #pragma unroll
    for (int j = 0; j < 4; ++j)
      acc[i][j] = (f32x4){0.f, 0.f, 0.f, 0.f};

  for (int k = 0; k < klen; k += 32){
    f16x8 af[4], bfr[4];
    #pragma unroll
    for (int i = 0; i < 4; ++i){
      af[i]  = *(const f16x8*)(Ap + (size_t)i * 16 * K + k);
      bfr[i] = *(const f16x8*)(Bp + (size_t)i * 16 * K + k);
    }
    #pragma unroll
    for (int i = 0; i < 4; ++i)
      #pragma unroll
      for (int j = 0; j < 4; ++j)
        acc[i][j] = mfma16(af[i], bfr[j], acc[i][j]);
  }

  if (MODE == 0){
    float bv[4];
    #pragma unroll
    for (int j = 0; j < 4; ++j){
      int g = Nb + j*16 + lr;
      bv[j] = bias1[g] + (g < 512 ? bias2[g] : 0.f);
    }
    #pragma unroll
    for (int i = 0; i < 4; ++i)
      #pragma unroll
      for (int r = 0; r < 4; ++r){
        int row = Mb + i*16 + lg*4 + r;
        int t = (int)(((uint64_t)(uint32_t)row * 167773u) >> 25);  // row/200 exact
        int b = row - t*200;
        #pragma unroll
        for (int j = 0; j < 4; ++j){
          int g = Nb + j*16 + lr;
          int q = g >> 8, jr = g & 255;
          size_t idx = ((((size_t)t*3 + q)*32 + ((jr>>5)*4 + ((jr>>2)&3)))*NBP + b)*8
                       + ((jr>>4)&1)*4 + (jr&3);
          Cb[idx] = (f16)(acc[i][j][r] + bv[j]);
        }
      }
  } else {
    #pragma unroll
    for (int i = 0; i < 4; ++i)
      #pragma unroll
      for (int j = 0; j < 4; ++j)
        #pragma unroll
        for (int r = 0; r < 4; ++r){
          int row = Mb + i*16 + lg*4 + r;
          int col = Nb + j*16 + lr;
          Cf[((size_t)blockIdx.z * 512 + row) * N + col] = acc[i][j][r];
        }
  }
}

// ---------------- persistent GRU layer: 13 blocks x 16 batch rows ------------
// Wave w owns hidden slice [32w,32w+32): gate rows {j,256+j,512+j}. Weights
// register-resident (192 VGPR). h double-buffered in LDS (chunked+swizzled).
// gi prefetched one step ahead via global_load_lds (wave-local, 0 VGPR).
// ONE raw barrier per step (lgkmcnt only — vmcnt stays in flight).
__global__ __launch_bounds__(512, 2)
void gru_layer(const f16* __restrict__ whh, const float* __restrict__ bhh,
               const f16* __restrict__ gi, f16* __restrict__ hs)
{
  // [0,16384): h bufs (2x8192, chunk layout). [16384,65536): gi bufs (2x24576)
  __shared__ __align__(16) unsigned char sm[16384 + 49152];
  const int tid = threadIdx.x;
  const int w  = tid >> 6, l = tid & 63;
  const int lr = l & 15, lg = l >> 4;
  const int b0 = blockIdx.x * BW;
  const bool bval = (b0 + lr) < NB;

  ((int4*)sm)[tid] = make_int4(0,0,0,0);   // zero h buf0 (512*16B = 8192)

  // gi DMA: per-lane global src; LDS dest = wave-uniform chunk base + lane*16
  const f16* glane = gi + ((size_t)((w*4 + lg)*NBP + b0 + lr))*8;
#define DMA_GI(P, Q) \
  __builtin_amdgcn_global_load_lds( \
      (const __attribute__((address_space(1))) void*)(glane + (Q)*(32*NBP*8)), \
      (__attribute__((address_space(3))) void*)(sm + 16384 + (P)*24576 + (Q)*8192 + w*1024), \
      16, 0, 0)

  DMA_GI(0,0); DMA_GI(0,1); DMA_GI(0,2);   // t=0 prefetch

  // weight fragments: A-frag lane l: row=lr (gate row), k = lg*8..+7 per kk
  f16x8 wA[6][8];
  #pragma unroll
  for (int q = 0; q < 3; ++q)
    #pragma unroll
    for (int t2 = 0; t2 < 2; ++t2)
      #pragma unroll
      for (int kk = 0; kk < 8; ++kk)
        wA[q*2+t2][kk] = *(const f16x8*)(whh + (size_t)(q*256 + w*32 + t2*16 + lr)*256 + kk*32 + lg*8);

  // n-gate bias, packed f16
  f16x4 bn[2];
  #pragma unroll
  for (int t2 = 0; t2 < 2; ++t2){
    float4 bv = *(const float4*)(bhh + 512 + w*32 + t2*16 + lg*4);
    bn[t2] = (f16x4){(f16)bv.x,(f16)bv.y,(f16)bv.z,(f16)bv.w};
  }

  // LDS addressing. h element (k,b) at byte (k>>5)*1024 + b*64 + (((k&31)*2)^((b&3)<<4))
  const int swz = (lr & 3) << 4;
  const int hrd = lr*64 + ((lg*16) ^ swz);           // + kk*1024 + p*8192 (B-frag read)
  const int hw0 = w*1024 + lr*64 + ((lg*8) ^ swz);   // own h, t2=0
  const int hw1 = hw0 ^ 32;                          // own h, t2=1
  const int gird = 16384 + w*1024 + l*16;            // + q*8192 + p*24576

  f16* hp = hs + (size_t)(b0 + lr)*HD + w*32 + lg*4;

  __syncthreads();

#define GRUSTEP(P) do { \
    f32x4 a00={0.f,0.f,0.f,0.f}, a01={0.f,0.f,0.f,0.f}, a10={0.f,0.f,0.f,0.f}; \
    f32x4 a11={0.f,0.f,0.f,0.f}, a20={0.f,0.f,0.f,0.f}, a21={0.f,0.f,0.f,0.f}; \
    _Pragma("unroll") \
    for (int kk = 0; kk < 8; ++kk){ \
      f16x8 hf = *(const f16x8*)(sm + (P)*8192 + kk*1024 + hrd); \
      a00 = mfma16(wA[0][kk], hf, a00); \
      a01 = mfma16(wA[1][kk], hf, a01); \
      a10 = mfma16(wA[2][kk], hf, a10); \
      a11 = mfma16(wA[3][kk], hf, a11); \
      a20 = mfma16(wA[4][kk], hf, a20); \
      a21 = mfma16(wA[5][kk], hf, a21); \
    } \
    asm volatile("s_waitcnt vmcnt(0)" ::: "memory"); \
    f16x8 g0 = *(const f16x8*)(sm + (P)*24576 + 0*8192 + gird); \
    f16x8 g1 = *(const f16x8*)(sm + (P)*24576 + 1*8192 + gird); \
    f16x8 g2 = *(const f16x8*)(sm + (P)*24576 + 2*8192 + gird); \
    f16x4 ho0 = *(const f16x4*)(sm + (P)*8192 + hw0); \
    f16x4 ho1 = *(const f16x4*)(sm + (P)*8192 + hw1); \
    glane += GI_TSTRIDE; \
    DMA_GI((P)^1, 0); DMA_GI((P)^1, 1); DMA_GI((P)^1, 2); \
    f16x4 hv0, hv1; \
    _Pragma("unroll") \
    for (int r = 0; r < 4; ++r){ \
      float rg = __builtin_amdgcn_rcpf(1.f + __builtin_amdgcn_exp2f(-LOG2E*((float)g0[r] + a00[r]))); \
      float zg = __builtin_amdgcn_rcpf(1.f + __builtin_amdgcn_exp2f(-LOG2E*((float)g1[r] + a10[r]))); \
      float hn = a20[r] + (float)bn[0][r]; \
      float aa = (float)g2[r] + rg*hn; \
      float ng = 2.f*__builtin_amdgcn_rcpf(1.f + __builtin_amdgcn_exp2f(-2.f*LOG2E*aa)) - 1.f; \
      float h  = ng + zg*((float)ho0[r] - ng); \
      hv0[r] = (f16)h; \
    } \
    _Pragma("unroll") \
    for (int r = 0; r < 4; ++r){ \
      float rg = __builtin_amdgcn_rcpf(1.f + __builtin_amdgcn_exp2f(-LOG2E*((float)g0[4+r] + a01[r]))); \
      float zg = __builtin_amdgcn_rcpf(1.f + __builtin_amdgcn_exp2f(-LOG2E*((float)g1[4+r] + a11[r]))); \
      float hn = a21[r] + (float)bn[1][r]; \
      float aa = (float)g2[4+r] + rg*hn; \
      float ng = 2.f*__builtin_amdgcn_rcpf(1.f + __builtin_amdgcn_exp2f(-2.f*LOG2E*aa)) - 1.f; \
      float h  = ng + zg*((float)ho1[r] - ng); \
      hv1[r] = (f16)h; \
    } \
    *(f16x4*)(sm + ((P)^1)*8192 + hw0) = hv0; \
    *(f16x4*)(sm + ((P)^1)*8192 + hw1) = hv1; \
    if (bval){ \
      *(f16x4*)(hp)      = hv0; \
      *(f16x4*)(hp + 16) = hv1; \
    } \
    hp += (size_t)NB*HD; \
    asm volatile("s_waitcnt lgkmcnt(0)" ::: "memory"); \
    __builtin_amdgcn_sched_barrier(0); \
    __builtin_amdgcn_s_barrier(); \
    __builtin_amdgcn_sched_barrier(0); \
  } while(0)

  // note: gi reads in GRUSTEP use (P)*24576 + gird where gird includes the
  // 16384 base, i.e. absolute byte 16384 + P*24576 + q*8192 + w*1024 + l*16.
  for (int th = 0; th < SEQ/2; ++th){
    GRUSTEP(0);
    GRUSTEP(1);
  }
#undef GRUSTEP
#undef DMA_GI
}

// ---------------- LayerNorm(hidden) + ReLU, in place on fp16 [rows][256] -----
__global__ __launch_bounds__(256)
void ln_relu(f16* __restrict__ hs, const float* __restrict__ lnw,
             const float* __restrict__ lnb)
{
  __shared__ float lds[8];
  const int tid = threadIdx.x;
  const int w = tid >> 6;
  const float gw = lnw[tid], gb = lnb[tid];
  for (int row = blockIdx.x; row < SEQ * NB; row += gridDim.x){
    f16* p = hs + (size_t)row * HD;
    float v = (float)p[tid];
    float s = v, q = v * v;
    #pragma unroll
    for (int off = 32; off; off >>= 1){
      s += __shfl_down(s, off);
      q += __shfl_down(q, off);
    }
    if ((tid & 63) == 0){ lds[w] = s; lds[4 + w] = q; }
    __syncthreads();
    float S = lds[0] + lds[1] + lds[2] + lds[3];
    float Q = lds[4] + lds[5] + lds[6] + lds[7];
    float mu = S * (1.f / HD);
    float var = Q * (1.f / HD) - mu * mu;
    float y = (v - mu) * rsqrtf(var + 1e-5f) * gw + gb;
    p[tid] = (f16)fmaxf(y, 0.f);
    __syncthreads();
  }
}

// ---------------- BatchNorm over axis0 (batch stats) + ReLU ------------------
__global__ __launch_bounds__(512)
void bn_relu(const float* __restrict__ part, const float* __restrict__ g,
             const float* __restrict__ b, float* __restrict__ z)
{
  __shared__ float lds[16];
  const int o = blockIdx.x, s = threadIdx.x, w = s >> 6;
  float y = 0.f;
  #pragma unroll
  for (int p = 0; p < 8; ++p) y += part[((size_t)p * 512 + o) * 512 + s];
  float su = y, q = y * y;
  #pragma unroll
  for (int off = 32; off; off >>= 1){
    su += __shfl_down(su, off);
    q  += __shfl_down(q, off);
  }
  if ((s & 63) == 0){ lds[w] = su; lds[8 + w] = q; }
  __syncthreads();
  float S = 0.f, Q = 0.f;
  #pragma unroll
  for (int i = 0; i < 8; ++i){ S += lds[i]; Q += lds[8 + i]; }
  float mu = S * (1.f / 512.f);
  float var = Q * (1.f / 512.f) - mu * mu;
  float zz = fmaxf((y - mu) * rsqrtf(var + 1e-5f) * g[o] + b[o], 0.f);
  z[(size_t)o * 512 + s] = zz;   // stored transposed [o][s]
}

// ---------------- fc3: out[s][c] = sum_o z[o][s]*w[c][o] + b[c] --------------
__global__ __launch_bounds__(256)
void fc3_k(const float* __restrict__ z, const float* __restrict__ w,
           const float* __restrict__ b, float* __restrict__ out)
{
  __shared__ float lds[12];
  const int s = blockIdx.x, tid = threadIdx.x, wv = tid >> 6;
  float a0 = 0.f, a1 = 0.f, a2 = 0.f;
  for (int o = tid; o < 512; o += 256){
    float zz = z[(size_t)o * 512 + s];
    a0 += zz * w[o];
    a1 += zz * w[512 + o];
    a2 += zz * w[1024 + o];
  }
  #pragma unroll
  for (int off = 32; off; off >>= 1){
    a0 += __shfl_down(a0, off);
    a1 += __shfl_down(a1, off);
    a2 += __shfl_down(a2, off);
  }
  if ((tid & 63) == 0){ lds[wv] = a0; lds[4 + wv] = a1; lds[8 + wv] = a2; }
  __syncthreads();
  if (tid == 0){
    out[s*3 + 0] = lds[0] + lds[1] + lds[2]  + lds[3]  + b[0];
    out[s*3 + 1] = lds[4] + lds[5] + lds[6]  + lds[7]  + b[1];
    out[s*3 + 2] = lds[8] + lds[9] + lds[10] + lds[11] + b[2];
  }
}

extern "C" void kernel_launch(void* const* d_in, const int* in_sizes, int n_in,
                              void* d_out, int out_size, void* d_ws, size_t ws_size,
                              hipStream_t stream)
{
  (void)in_sizes; (void)n_in; (void)out_size; (void)ws_size;
  const float* x    = (const float*)d_in[0];
  const float* wih0 = (const float*)d_in[1];
  const float* whh0 = (const float*)d_in[2];
  const float* bih0 = (const float*)d_in[3];
  const float* bhh0 = (const float*)d_in[4];
  const float* wih1 = (const float*)d_in[5];
  const float* whh1 = (const float*)d_in[6];
  const float* bih1 = (const float*)d_in[7];
  const float* bhh1 = (const float*)d_in[8];
  const float* lnw  = (const float*)d_in[9];
  const float* lnb  = (const float*)d_in[10];
  const float* fc2w = (const float*)d_in[11];
  // d_in[12] = fc2_b skipped: BN mean-centering cancels constant column bias.
  const float* bng  = (const float*)d_in[13];
  const float* bnb  = (const float*)d_in[14];
  const float* fc3w = (const float*)d_in[15];
  const float* fc3b = (const float*)d_in[16];
  float* out = (float*)d_out;

  char* ws = (char*)d_ws;
  size_t off = 0;
  auto alloc = [&](size_t bytes) -> void* {
    void* p = ws + off; off += (bytes + 255) & ~(size_t)255; return p;
  };
  f16* GI     = (f16*)alloc((size_t)SEQ*GI_TSTRIDE*2);  // 163.6 MB (permuted layout)
  f16* X16    = (f16*)alloc((size_t)SEQ*NB*64*2);       // 13.1 MB
  f16* WI0    = (f16*)alloc((size_t)768*64*2);
  f16* WH0    = (f16*)alloc((size_t)768*256*2);
  f16* WI1    = (f16*)alloc((size_t)768*256*2);
  f16* WH1    = (f16*)alloc((size_t)768*256*2);
  f16* HS0    = (f16*)alloc((size_t)SEQ*NB*256*2);      // 52.4 MB
  f16* HS1    = (f16*)alloc((size_t)SEQ*NB*256*2);      // 52.4 MB
  float* PART = (float*)alloc((size_t)8*512*512*4);     // 8.4 MB
  float* Z    = (float*)alloc((size_t)512*512*4);       // 1 MB (total ~292 MB)
  f16* FC2W   = GI;   // aliased: GI dead after gru1, FC2W converted after gru1

  cvt_f32_f16<<<2048,256,0,stream>>>(x,    X16,  SEQ*NB*64/4);
  cvt_f32_f16<<<64,  256,0,stream>>>(wih0, WI0,  768*64/4);
  cvt_f32_f16<<<192, 256,0,stream>>>(whh0, WH0,  768*256/4);
  cvt_f32_f16<<<192, 256,0,stream>>>(wih1, WI1,  768*256/4);
  cvt_f32_f16<<<192, 256,0,stream>>>(whh1, WH1,  768*256/4);

  dim3 g0(800, 6, 1);
  // gi0 = x @ w_ih0^T + b_ih0 (+ b_hh0 for r,z gates), permuted layout
  gemm_bt<0><<<g0, 256, 0, stream>>>(X16, WI0, GI, nullptr, bih0, bhh0, 64, GD, 64);
  gru_layer<<<NBLK, 512, 0, stream>>>(WH0, bhh0, GI, HS0);
  gemm_bt<0><<<g0, 256, 0, stream>>>(HS0, WI1, GI, nullptr, bih1, bhh1, 256, GD, 256);
  gru_layer<<<NBLK, 512, 0, stream>>>(WH1, bhh1, GI, HS1);
  // LayerNorm + ReLU in place -> hflat (fp16, layout already (512, 51200))
  ln_relu<<<2048, 256, 0, stream>>>(HS1, lnw, lnb);
  // fc2 weights converted now (GI dead), into GI-aliased buffer
  cvt_f32_f16<<<4096,256,0,stream>>>(fc2w, FC2W, 512*51200/4);
  dim3 g2(4, 4, 8);
  gemm_bt<1><<<g2, 256, 0, stream>>>(FC2W, HS1, nullptr, PART, nullptr, nullptr, 51200, 512, 6400);
  bn_relu<<<512, 512, 0, stream>>>(PART, bng, bnb, Z);
  fc3_k<<<512, 256, 0, stream>>>(Z, fc3w, fc3b, out);
}

// Round 3
// 2878.634 us; speedup vs baseline: 1.3767x; 1.0055x over previous
//
#include <hip/hip_runtime.h>
#include <stdint.h>

typedef _Float16 f16;
typedef _Float16 f16x4 __attribute__((ext_vector_type(4)));
typedef _Float16 f16x8 __attribute__((ext_vector_type(8)));
typedef float f32x4 __attribute__((ext_vector_type(4)));

#define SEQ 512
#define NB  200
#define HD  256
#define GD  768
#define BW  16
#define NBLK 13           // ceil(200/16)
#define NBP 208           // padded batch for GI layout
#define GI_TSTRIDE (3*32*NBP*8)   // halves per timestep = 159744
#define LOG2E 1.44269504f

__device__ __forceinline__ f32x4 mfma16(f16x8 a, f16x8 b, f32x4 c){
  return __builtin_amdgcn_mfma_f32_16x16x32_f16(a, b, c, 0, 0, 0);
}

// ---------------- fp32 -> fp16 convert ----------------
__global__ void cvt_f32_f16(const float* __restrict__ src, f16* __restrict__ dst, int n4){
  int i = blockIdx.x * blockDim.x + threadIdx.x;
  int stride = gridDim.x * blockDim.x;
  for (; i < n4; i += stride){
    float4 v = ((const float4*)src)[i];
    f16x4 o = { (f16)v.x, (f16)v.y, (f16)v.z, (f16)v.w };
    ((f16x4*)dst)[i] = o;
  }
}

// ---------------- GEMM: C[m][n] = sum_k A[m][k]*B[n][k] (both K-major) -------
// MODE 0: fp16 out into PERMUTED GI layout, bias1[col] (+bias2[col] for col<512).
// MODE 1: fp32 partials out[(z*512+row)*N+col].  grid (M/128, N/128, splits)
template<int MODE>
__global__ __launch_bounds__(256, 2)
void gemm_bt(const f16* __restrict__ A, const f16* __restrict__ B,
             f16* __restrict__ Cb, float* __restrict__ Cf,
             const float* __restrict__ bias1, const float* __restrict__ bias2,
             int K, int N, int klen)
{
  const int l  = threadIdx.x & 63;
  const int w  = threadIdx.x >> 6;
  const int lr = l & 15, lg = l >> 4;
  const int Mb = blockIdx.x * 128 + (w >> 1) * 64;
  const int Nb = blockIdx.y * 128 + (w & 1) * 64;
  const int kb = blockIdx.z * klen;

  const f16* Ap = A + (size_t)(Mb + lr) * K + kb + lg * 8;
  const f16* Bp = B + (size_t)(Nb + lr) * K + kb + lg * 8;

  f32x4 acc[4][4];
  #pragma unroll
  for (int i = 0; i < 4; ++i)
    #pragma unroll
    for (int j = 0; j < 4; ++j)
      acc[i][j] = (f32x4){0.f, 0.f, 0.f, 0.f};

  for (int k = 0; k < klen; k += 32){
    f16x8 af[4], bfr[4];
    #pragma unroll
    for (int i = 0; i < 4; ++i){
      af[i]  = *(const f16x8*)(Ap + (size_t)i * 16 * K + k);
      bfr[i] = *(const f16x8*)(Bp + (size_t)i * 16 * K + k);
    }
    #pragma unroll
    for (int i = 0; i < 4; ++i)
      #pragma unroll
      for (int j = 0; j < 4; ++j)
        acc[i][j] = mfma16(af[i], bfr[j], acc[i][j]);
  }

  if (MODE == 0){
    float bv[4];
    #pragma unroll
    for (int j = 0; j < 4; ++j){
      int g = Nb + j*16 + lr;
      bv[j] = bias1[g] + (g < 512 ? bias2[g] : 0.f);
    }
    #pragma unroll
    for (int i = 0; i < 4; ++i)
      #pragma unroll
      for (int r = 0; r < 4; ++r){
        int row = Mb + i*16 + lg*4 + r;
        int t = (int)(((uint64_t)(uint32_t)row * 167773u) >> 25);  // row/200 exact
        int b = row - t*200;
        #pragma unroll
        for (int j = 0; j < 4; ++j){
          int g = Nb + j*16 + lr;
          int q = g >> 8, jr = g & 255;
          size_t idx = ((((size_t)t*3 + q)*32 + ((jr>>5)*4 + ((jr>>2)&3)))*NBP + b)*8
                       + ((jr>>4)&1)*4 + (jr&3);
          Cb[idx] = (f16)(acc[i][j][r] + bv[j]);
        }
      }
  } else {
    #pragma unroll
    for (int i = 0; i < 4; ++i)
      #pragma unroll
      for (int j = 0; j < 4; ++j)
        #pragma unroll
        for (int r = 0; r < 4; ++r){
          int row = Mb + i*16 + lg*4 + r;
          int col = Nb + j*16 + lr;
          Cf[((size_t)blockIdx.z * 512 + row) * N + col] = acc[i][j][r];
        }
  }
}

// ---------------- persistent GRU layer: 13 blocks x 16 batch rows ------------
// Wave w owns hidden slice [32w,32w+32). Weights PINNED register-resident
// (192 VGPR, opaque asm + waves_per_eu(2,2) so remat is impossible).
// h double-buffered in LDS, swizzle c(b)=(b^(b>>2))&3 (conflict-free b128).
// gi prefetched one step ahead via global_load_lds (wave-local, 0 VGPR).
__global__ __launch_bounds__(512)
__attribute__((amdgpu_waves_per_eu(2, 2)))
void gru_layer(const f16* __restrict__ whh, const float* __restrict__ bhh,
               const f16* __restrict__ gi, f16* __restrict__ hs)
{
  // [0,16384): h bufs (2x8192, chunk layout). [16384,65536): gi bufs (2x24576)
  __shared__ __align__(16) unsigned char sm[16384 + 49152];
  const int tid = threadIdx.x;
  const int w  = tid >> 6, l = tid & 63;
  const int lr = l & 15, lg = l >> 4;
  const int b0 = blockIdx.x * BW;
  const bool bval = (b0 + lr) < NB;

  ((int4*)sm)[tid] = make_int4(0,0,0,0);   // zero h buf0 (512*16B = 8192)

  // gi DMA: per-lane global src; LDS dest = wave-uniform chunk base + lane*16
  const f16* glane = gi + ((size_t)((w*4 + lg)*NBP + b0 + lr))*8;
#define DMA_GI(P, Q) \
  __builtin_amdgcn_global_load_lds( \
      (const __attribute__((address_space(1))) void*)(glane + (Q)*(32*NBP*8)), \
      (__attribute__((address_space(3))) void*)(sm + 16384 + (P)*24576 + (Q)*8192 + w*1024), \
      16, 0, 0)

  DMA_GI(0,0); DMA_GI(0,1); DMA_GI(0,2);   // t=0 prefetch

  // weight fragments: A-frag lane l: row=lr (gate row), k = lg*8..+7 per kk
  f16x8 wA[6][8];
  #pragma unroll
  for (int q = 0; q < 3; ++q)
    #pragma unroll
    for (int t2 = 0; t2 < 2; ++t2)
      #pragma unroll
      for (int kk = 0; kk < 8; ++kk)
        wA[q*2+t2][kk] = *(const f16x8*)(whh + (size_t)(q*256 + w*32 + t2*16 + lr)*256 + kk*32 + lg*8);

  // n-gate bias, packed f16
  f16x4 bn[2];
  #pragma unroll
  for (int t2 = 0; t2 < 2; ++t2){
    float4 bv = *(const float4*)(bhh + 512 + w*32 + t2*16 + lg*4);
    bn[t2] = (f16x4){(f16)bv.x,(f16)bv.y,(f16)bv.z,(f16)bv.w};
  }

  // Pin weights in VGPRs: opaque to the optimizer -> cannot rematerialize.
  #pragma unroll
  for (int i = 0; i < 6; ++i)
    #pragma unroll
    for (int kk = 0; kk < 8; ++kk)
      asm volatile("" : "+v"(wA[i][kk]));
  asm volatile("" : "+v"(bn[0]), "+v"(bn[1]));

  // LDS addressing. h element (k,b) at byte:
  //   (k>>5)*1024 + b*64 + (((k&31)*2) ^ (c(b)<<4)),  c(b) = (b ^ (b>>2)) & 3
  const int cswz = ((lr ^ (lr >> 2)) & 3) << 4;
  const int hrd = lr*64 + ((lg*16) ^ cswz);           // + kk*1024 + p*8192
  const int hw0 = w*1024 + lr*64 + ((lg*8) ^ cswz);   // own h, t2=0
  const int hw1 = hw0 ^ 32;                           // own h, t2=1
  const int gird = 16384 + w*1024 + l*16;             // + q*8192 + p*24576

  f16* hp = hs + (size_t)(b0 + lr)*HD + w*32 + lg*4;

  __syncthreads();

#define GRUSTEP(P) do { \
    f32x4 a00={0.f,0.f,0.f,0.f}, a01={0.f,0.f,0.f,0.f}, a10={0.f,0.f,0.f,0.f}; \
    f32x4 a11={0.f,0.f,0.f,0.f}, a20={0.f,0.f,0.f,0.f}, a21={0.f,0.f,0.f,0.f}; \
    _Pragma("unroll") \
    for (int kk = 0; kk < 8; ++kk){ \
      f16x8 hf = *(const f16x8*)(sm + (P)*8192 + kk*1024 + hrd); \
      a00 = mfma16(wA[0][kk], hf, a00); \
      a01 = mfma16(wA[1][kk], hf, a01); \
      a10 = mfma16(wA[2][kk], hf, a10); \
      a11 = mfma16(wA[3][kk], hf, a11); \
      a20 = mfma16(wA[4][kk], hf, a20); \
      a21 = mfma16(wA[5][kk], hf, a21); \
    } \
    asm volatile("s_waitcnt vmcnt(0)" ::: "memory"); \
    f16x8 g0 = *(const f16x8*)(sm + (P)*24576 + 0*8192 + gird); \
    f16x8 g1 = *(const f16x8*)(sm + (P)*24576 + 1*8192 + gird); \
    f16x8 g2 = *(const f16x8*)(sm + (P)*24576 + 2*8192 + gird); \
    f16x4 ho0 = *(const f16x4*)(sm + (P)*8192 + hw0); \
    f16x4 ho1 = *(const f16x4*)(sm + (P)*8192 + hw1); \
    glane += GI_TSTRIDE; \
    DMA_GI((P)^1, 0); DMA_GI((P)^1, 1); DMA_GI((P)^1, 2); \
    f16x4 hv0, hv1; \
    _Pragma("unroll") \
    for (int r = 0; r < 4; ++r){ \
      float rg = __builtin_amdgcn_rcpf(1.f + __builtin_amdgcn_exp2f(-LOG2E*((float)g0[r] + a00[r]))); \
      float zg = __builtin_amdgcn_rcpf(1.f + __builtin_amdgcn_exp2f(-LOG2E*((float)g1[r] + a10[r]))); \
      float hn = a20[r] + (float)bn[0][r]; \
      float aa = (float)g2[r] + rg*hn; \
      float ng = 2.f*__builtin_amdgcn_rcpf(1.f + __builtin_amdgcn_exp2f(-2.f*LOG2E*aa)) - 1.f; \
      float h  = ng + zg*((float)ho0[r] - ng); \
      hv0[r] = (f16)h; \
    } \
    _Pragma("unroll") \
    for (int r = 0; r < 4; ++r){ \
      float rg = __builtin_amdgcn_rcpf(1.f + __builtin_amdgcn_exp2f(-LOG2E*((float)g0[4+r] + a01[r]))); \
      float zg = __builtin_amdgcn_rcpf(1.f + __builtin_amdgcn_exp2f(-LOG2E*((float)g1[4+r] + a11[r]))); \
      float hn = a21[r] + (float)bn[1][r]; \
      float aa = (float)g2[4+r] + rg*hn; \
      float ng = 2.f*__builtin_amdgcn_rcpf(1.f + __builtin_amdgcn_exp2f(-2.f*LOG2E*aa)) - 1.f; \
      float h  = ng + zg*((float)ho1[r] - ng); \
      hv1[r] = (f16)h; \
    } \
    *(f16x4*)(sm + ((P)^1)*8192 + hw0) = hv0; \
    *(f16x4*)(sm + ((P)^1)*8192 + hw1) = hv1; \
    if (bval){ \
      *(f16x4*)(hp)      = hv0; \
      *(f16x4*)(hp + 16) = hv1; \
    } \
    hp += (size_t)NB*HD; \
    asm volatile("s_waitcnt lgkmcnt(0)" ::: "memory"); \
    __builtin_amdgcn_sched_barrier(0); \
    __builtin_amdgcn_s_barrier(); \
    __builtin_amdgcn_sched_barrier(0); \
  } while(0)

  for (int th = 0; th < SEQ/2; ++th){
    GRUSTEP(0);
    GRUSTEP(1);
  }
#undef GRUSTEP
#undef DMA_GI
}

// ---------------- LayerNorm(hidden) + ReLU, in place on fp16 [rows][256] -----
__global__ __launch_bounds__(256)
void ln_relu(f16* __restrict__ hs, const float* __restrict__ lnw,
             const float* __restrict__ lnb)
{
  __shared__ float lds[8];
  const int tid = threadIdx.x;
  const int w = tid >> 6;
  const float gw = lnw[tid], gb = lnb[tid];
  for (int row = blockIdx.x; row < SEQ * NB; row += gridDim.x){
    f16* p = hs + (size_t)row * HD;
    float v = (float)p[tid];
    float s = v, q = v * v;
    #pragma unroll
    for (int off = 32; off; off >>= 1){
      s += __shfl_down(s, off);
      q += __shfl_down(q, off);
    }
    if ((tid & 63) == 0){ lds[w] = s; lds[4 + w] = q; }
    __syncthreads();
    float S = lds[0] + lds[1] + lds[2] + lds[3];
    float Q = lds[4] + lds[5] + lds[6] + lds[7];
    float mu = S * (1.f / HD);
    float var = Q * (1.f / HD) - mu * mu;
    float y = (v - mu) * rsqrtf(var + 1e-5f) * gw + gb;
    p[tid] = (f16)fmaxf(y, 0.f);
    __syncthreads();
  }
}

// ---------------- BatchNorm over axis0 (batch stats) + ReLU ------------------
__global__ __launch_bounds__(512)
void bn_relu(const float* __restrict__ part, const float* __restrict__ g,
             const float* __restrict__ b, float* __restrict__ z)
{
  __shared__ float lds[16];
  const int o = blockIdx.x, s = threadIdx.x, w = s >> 6;
  float y = 0.f;
  #pragma unroll
  for (int p = 0; p < 8; ++p) y += part[((size_t)p * 512 + o) * 512 + s];
  float su = y, q = y * y;
  #pragma unroll
  for (int off = 32; off; off >>= 1){
    su += __shfl_down(su, off);
    q  += __shfl_down(q, off);
  }
  if ((s & 63) == 0){ lds[w] = su; lds[8 + w] = q; }
  __syncthreads();
  float S = 0.f, Q = 0.f;
  #pragma unroll
  for (int i = 0; i < 8; ++i){ S += lds[i]; Q += lds[8 + i]; }
  float mu = S * (1.f / 512.f);
  float var = Q * (1.f / 512.f) - mu * mu;
  float zz = fmaxf((y - mu) * rsqrtf(var + 1e-5f) * g[o] + b[o], 0.f);
  z[(size_t)o * 512 + s] = zz;   // stored transposed [o][s]
}

// ---------------- fc3: out[s][c] = sum_o z[o][s]*w[c][o] + b[c] --------------
__global__ __launch_bounds__(256)
void fc3_k(const float* __restrict__ z, const float* __restrict__ w,
           const float* __restrict__ b, float* __restrict__ out)
{
  __shared__ float lds[12];
  const int s = blockIdx.x, tid = threadIdx.x, wv = tid >> 6;
  float a0 = 0.f, a1 = 0.f, a2 = 0.f;
  for (int o = tid; o < 512; o += 256){
    float zz = z[(size_t)o * 512 + s];
    a0 += zz * w[o];
    a1 += zz * w[512 + o];
    a2 += zz * w[1024 + o];
  }
  #pragma unroll
  for (int off = 32; off; off >>= 1){
    a0 += __shfl_down(a0, off);
    a1 += __shfl_down(a1, off);
    a2 += __shfl_down(a2, off);
  }
  if ((tid & 63) == 0){ lds[wv] = a0; lds[4 + wv] = a1; lds[8 + wv] = a2; }
  __syncthreads();
  if (tid == 0){
    out[s*3 + 0] = lds[0] + lds[1] + lds[2]  + lds[3]  + b[0];
    out[s*3 + 1] = lds[4] + lds[5] + lds[6]  + lds[7]  + b[1];
    out[s*3 + 2] = lds[8] + lds[9] + lds[10] + lds[11] + b[2];
  }
}

extern "C" void kernel_launch(void* const* d_in, const int* in_sizes, int n_in,
                              void* d_out, int out_size, void* d_ws, size_t ws_size,
                              hipStream_t stream)
{
  (void)in_sizes; (void)n_in; (void)out_size; (void)ws_size;
  const float* x    = (const float*)d_in[0];
  const float* wih0 = (const float*)d_in[1];
  const float* whh0 = (const float*)d_in[2];
  const float* bih0 = (const float*)d_in[3];
  const float* bhh0 = (const float*)d_in[4];
  const float* wih1 = (const float*)d_in[5];
  const float* whh1 = (const float*)d_in[6];
  const float* bih1 = (const float*)d_in[7];
  const float* bhh1 = (const float*)d_in[8];
  const float* lnw  = (const float*)d_in[9];
  const float* lnb  = (const float*)d_in[10];
  const float* fc2w = (const float*)d_in[11];
  // d_in[12] = fc2_b skipped: BN mean-centering cancels constant column bias.
  const float* bng  = (const float*)d_in[13];
  const float* bnb  = (const float*)d_in[14];
  const float* fc3w = (const float*)d_in[15];
  const float* fc3b = (const float*)d_in[16];
  float* out = (float*)d_out;

  char* ws = (char*)d_ws;
  size_t off = 0;
  auto alloc = [&](size_t bytes) -> void* {
    void* p = ws + off; off += (bytes + 255) & ~(size_t)255; return p;
  };
  f16* GI     = (f16*)alloc((size_t)SEQ*GI_TSTRIDE*2);  // 163.6 MB (permuted layout)
  f16* X16    = (f16*)alloc((size_t)SEQ*NB*64*2);       // 13.1 MB
  f16* WI0    = (f16*)alloc((size_t)768*64*2);
  f16* WH0    = (f16*)alloc((size_t)768*256*2);
  f16* WI1    = (f16*)alloc((size_t)768*256*2);
  f16* WH1    = (f16*)alloc((size_t)768*256*2);
  f16* HS0    = (f16*)alloc((size_t)SEQ*NB*256*2);      // 52.4 MB
  f16* HS1    = (f16*)alloc((size_t)SEQ*NB*256*2);      // 52.4 MB
  float* PART = (float*)alloc((size_t)8*512*512*4);     // 8.4 MB
  float* Z    = (float*)alloc((size_t)512*512*4);       // 1 MB (total ~292 MB)
  f16* FC2W   = GI;   // aliased: GI dead after gru1, FC2W converted after gru1

  cvt_f32_f16<<<2048,256,0,stream>>>(x,    X16,  SEQ*NB*64/4);
  cvt_f32_f16<<<64,  256,0,stream>>>(wih0, WI0,  768*64/4);
  cvt_f32_f16<<<192, 256,0,stream>>>(whh0, WH0,  768*256/4);
  cvt_f32_f16<<<192, 256,0,stream>>>(wih1, WI1,  768*256/4);
  cvt_f32_f16<<<192, 256,0,stream>>>(whh1, WH1,  768*256/4);

  dim3 g0(800, 6, 1);
  // gi0 = x @ w_ih0^T + b_ih0 (+ b_hh0 for r,z gates), permuted layout
  gemm_bt<0><<<g0, 256, 0, stream>>>(X16, WI0, GI, nullptr, bih0, bhh0, 64, GD, 64);
  gru_layer<<<NBLK, 512, 0, stream>>>(WH0, bhh0, GI, HS0);
  gemm_bt<0><<<g0, 256, 0, stream>>>(HS0, WI1, GI, nullptr, bih1, bhh1, 256, GD, 256);
  gru_layer<<<NBLK, 512, 0, stream>>>(WH1, bhh1, GI, HS1);
  // LayerNorm + ReLU in place -> hflat (fp16, layout already (512, 51200))
  ln_relu<<<2048, 256, 0, stream>>>(HS1, lnw, lnb);
  // fc2 weights converted now (GI dead), into GI-aliased buffer
  cvt_f32_f16<<<4096,256,0,stream>>>(fc2w, FC2W, 512*51200/4);
  dim3 g2(4, 4, 8);
  gemm_bt<1><<<g2, 256, 0, stream>>>(FC2W, HS1, nullptr, PART, nullptr, nullptr, 51200, 512, 6400);
  bn_relu<<<512, 512, 0, stream>>>(PART, bng, bnb, Z);
  fc3_k<<<512, 256, 0, stream>>>(Z, fc3w, fc3b, out);
}

// Round 4
// 2778.698 us; speedup vs baseline: 1.4263x; 1.0360x over previous
//
#include <hip/hip_runtime.h>
#include <stdint.h>

typedef _Float16 f16;
typedef _Float16 f16x4 __attribute__((ext_vector_type(4)));
typedef _Float16 f16x8 __attribute__((ext_vector_type(8)));
typedef float f32x4 __attribute__((ext_vector_type(4)));

#define SEQ 512
#define NB  200
#define HD  256
#define GD  768
#define BW  16
#define NBLK 13           // ceil(200/16)
#define NBP 208           // padded batch for GI layout
#define GI_TSTRIDE (3*32*NBP*8)   // halves per timestep = 159744
#define LOG2E 1.44269504f

__device__ __forceinline__ f32x4 mfma16(f16x8 a, f16x8 b, f32x4 c){
  return __builtin_amdgcn_mfma_f32_16x16x32_f16(a, b, c, 0, 0, 0);
}

// ---------------- fp32 -> fp16 convert ----------------
__global__ void cvt_f32_f16(const float* __restrict__ src, f16* __restrict__ dst, int n4){
  int i = blockIdx.x * blockDim.x + threadIdx.x;
  int stride = gridDim.x * blockDim.x;
  for (; i < n4; i += stride){
    float4 v = ((const float4*)src)[i];
    f16x4 o = { (f16)v.x, (f16)v.y, (f16)v.z, (f16)v.w };
    ((f16x4*)dst)[i] = o;
  }
}

// ---------------- GEMM: C[m][n] = sum_k A[m][k]*B[n][k] (both K-major) -------
// MODE 0: fp16 out into PERMUTED GI layout, bias1[col] (+bias2[col] for col<512).
// MODE 1: fp32 partials out[(z*512+row)*N+col].  grid (M/128, N/128, splits)
template<int MODE>
__global__ __launch_bounds__(256, 2)
void gemm_bt(const f16* __restrict__ A, const f16* __restrict__ B,
             f16* __restrict__ Cb, float* __restrict__ Cf,
             const float* __restrict__ bias1, const float* __restrict__ bias2,
             int K, int N, int klen)
{
  const int l  = threadIdx.x & 63;
  const int w  = threadIdx.x >> 6;
  const int lr = l & 15, lg = l >> 4;
  const int Mb = blockIdx.x * 128 + (w >> 1) * 64;
  const int Nb = blockIdx.y * 128 + (w & 1) * 64;
  const int kb = blockIdx.z * klen;

  const f16* Ap = A + (size_t)(Mb + lr) * K + kb + lg * 8;
  const f16* Bp = B + (size_t)(Nb + lr) * K + kb + lg * 8;

  f32x4 acc[4][4];
  #pragma unroll
  for (int i = 0; i < 4; ++i)
    #pragma unroll
    for (int j = 0; j < 4; ++j)
      acc[i][j] = (f32x4){0.f, 0.f, 0.f, 0.f};

  for (int k = 0; k < klen; k += 32){
    f16x8 af[4], bfr[4];
    #pragma unroll
    for (int i = 0; i < 4; ++i){
      af[i]  = *(const f16x8*)(Ap + (size_t)i * 16 * K + k);
      bfr[i] = *(const f16x8*)(Bp + (size_t)i * 16 * K + k);
    }
    #pragma unroll
    for (int i = 0; i < 4; ++i)
      #pragma unroll
      for (int j = 0; j < 4; ++j)
        acc[i][j] = mfma16(af[i], bfr[j], acc[i][j]);
  }

  if (MODE == 0){
    float bv[4];
    #pragma unroll
    for (int j = 0; j < 4; ++j){
      int g = Nb + j*16 + lr;
      bv[j] = bias1[g] + (g < 512 ? bias2[g] : 0.f);
    }
    #pragma unroll
    for (int i = 0; i < 4; ++i)
      #pragma unroll
      for (int r = 0; r < 4; ++r){
        int row = Mb + i*16 + lg*4 + r;
        int t = (int)(((uint64_t)(uint32_t)row * 167773u) >> 25);  // row/200 exact
        int b = row - t*200;
        #pragma unroll
        for (int j = 0; j < 4; ++j){
          int g = Nb + j*16 + lr;
          int q = g >> 8, jr = g & 255;
          size_t idx = ((((size_t)t*3 + q)*32 + ((jr>>5)*4 + ((jr>>2)&3)))*NBP + b)*8
                       + ((jr>>4)&1)*4 + (jr&3);
          Cb[idx] = (f16)(acc[i][j][r] + bv[j]);
        }
      }
  } else {
    #pragma unroll
    for (int i = 0; i < 4; ++i)
      #pragma unroll
      for (int j = 0; j < 4; ++j)
        #pragma unroll
        for (int r = 0; r < 4; ++r){
          int row = Mb + i*16 + lg*4 + r;
          int col = Nb + j*16 + lr;
          Cf[((size_t)blockIdx.z * 512 + row) * N + col] = acc[i][j][r];
        }
  }
}

// ---------------- persistent GRU layer: 13 blocks x 16 batch rows ------------
// Wave w owns hidden slice [32w,32w+32). Weights register-resident (192 VGPR).
// KEY: LDS padded to 90112B so only 1 block/CU fits -> backend's LDS-derived
// occupancy is 2 waves/EU -> VGPR budget 256 (at 64KB it derived 4 waves/EU,
// capped at 128 regs, and spilled the weights to scratch = L2 refetch/step).
// h double-buffered in LDS, swizzle c(b)=(b^(b>>2))&3 (conflict-free b128).
// gi prefetched one step ahead via global_load_lds (wave-local, 0 VGPR).
// vmcnt(2) per step: waits the 3 gi DMAs, lets the 2 hs stores stay in flight.
__global__ __launch_bounds__(512, 2)
__attribute__((amdgpu_waves_per_eu(2, 2)))
void gru_layer(const f16* __restrict__ whh, const float* __restrict__ bhh,
               const f16* __restrict__ gi, f16* __restrict__ hs)
{
  // [0,16384): h bufs (2x8192). [16384,65536): gi bufs (2x24576). rest: pad.
  __shared__ __align__(16) unsigned char sm[16384 + 49152 + 24576];
  const int tid = threadIdx.x;
  const int w  = tid >> 6, l = tid & 63;
  const int lr = l & 15, lg = l >> 4;
  const int b0 = blockIdx.x * BW;
  const bool bval = (b0 + lr) < NB;

  ((int4*)sm)[tid] = make_int4(0,0,0,0);   // zero h buf0 (512*16B = 8192)
  ((int4*)(sm + 65536))[tid] = make_int4(0,0,0,0);  // touch pad (keep it live)

  // gi DMA: per-lane global src; LDS dest = wave-uniform chunk base + lane*16
  const f16* glane = gi + ((size_t)((w*4 + lg)*NBP + b0 + lr))*8;
#define DMA_GI(P, Q) \
  __builtin_amdgcn_global_load_lds( \
      (const __attribute__((address_space(1))) void*)(glane + (Q)*(32*NBP*8)), \
      (__attribute__((address_space(3))) void*)(sm + 16384 + (P)*24576 + (Q)*8192 + w*1024), \
      16, 0, 0)

  DMA_GI(0,0); DMA_GI(0,1); DMA_GI(0,2);   // t=0 prefetch

  // weight fragments: A-frag lane l: row=lr (gate row), k = lg*8..+7 per kk
  f16x8 wA[6][8];
  #pragma unroll
  for (int q = 0; q < 3; ++q)
    #pragma unroll
    for (int t2 = 0; t2 < 2; ++t2)
      #pragma unroll
      for (int kk = 0; kk < 8; ++kk)
        wA[q*2+t2][kk] = *(const f16x8*)(whh + (size_t)(q*256 + w*32 + t2*16 + lr)*256 + kk*32 + lg*8);

  // n-gate bias, packed f16
  f16x4 bn[2];
  #pragma unroll
  for (int t2 = 0; t2 < 2; ++t2){
    float4 bv = *(const float4*)(bhh + 512 + w*32 + t2*16 + lg*4);
    bn[t2] = (f16x4){(f16)bv.x,(f16)bv.y,(f16)bv.z,(f16)bv.w};
  }

  // Pin weights in VGPRs: opaque to the optimizer -> cannot rematerialize.
  #pragma unroll
  for (int i = 0; i < 6; ++i)
    #pragma unroll
    for (int kk = 0; kk < 8; ++kk)
      asm volatile("" : "+v"(wA[i][kk]));
  asm volatile("" : "+v"(bn[0]), "+v"(bn[1]));

  // LDS addressing. h element (k,b) at byte:
  //   (k>>5)*1024 + b*64 + (((k&31)*2) ^ (c(b)<<4)),  c(b) = (b ^ (b>>2)) & 3
  const int cswz = ((lr ^ (lr >> 2)) & 3) << 4;
  const int hrd = lr*64 + ((lg*16) ^ cswz);           // + kk*1024 + p*8192
  const int hw0 = w*1024 + lr*64 + ((lg*8) ^ cswz);   // own h, t2=0
  const int hw1 = hw0 ^ 32;                           // own h, t2=1
  const int gird = 16384 + w*1024 + l*16;             // + q*8192 + p*24576

  f16* hp = hs + (size_t)(b0 + lr)*HD + w*32 + lg*4;

  asm volatile("s_waitcnt vmcnt(0)" ::: "memory");  // drain prologue DMA+loads
  __syncthreads();

#define GRUSTEP(P) do { \
    f32x4 a00={0.f,0.f,0.f,0.f}, a01={0.f,0.f,0.f,0.f}, a10={0.f,0.f,0.f,0.f}; \
    f32x4 a11={0.f,0.f,0.f,0.f}, a20={0.f,0.f,0.f,0.f}, a21={0.f,0.f,0.f,0.f}; \
    _Pragma("unroll") \
    for (int kk = 0; kk < 8; ++kk){ \
      f16x8 hf = *(const f16x8*)(sm + (P)*8192 + kk*1024 + hrd); \
      a00 = mfma16(wA[0][kk], hf, a00); \
      a01 = mfma16(wA[1][kk], hf, a01); \
      a10 = mfma16(wA[2][kk], hf, a10); \
      a11 = mfma16(wA[3][kk], hf, a11); \
      a20 = mfma16(wA[4][kk], hf, a20); \
      a21 = mfma16(wA[5][kk], hf, a21); \
    } \
    asm volatile("s_waitcnt vmcnt(2)" ::: "memory"); \
    f16x8 g0 = *(const f16x8*)(sm + (P)*24576 + 0*8192 + gird); \
    f16x8 g1 = *(const f16x8*)(sm + (P)*24576 + 1*8192 + gird); \
    f16x8 g2 = *(const f16x8*)(sm + (P)*24576 + 2*8192 + gird); \
    f16x4 ho0 = *(const f16x4*)(sm + (P)*8192 + hw0); \
    f16x4 ho1 = *(const f16x4*)(sm + (P)*8192 + hw1); \
    glane += GI_TSTRIDE; \
    DMA_GI((P)^1, 0); DMA_GI((P)^1, 1); DMA_GI((P)^1, 2); \
    f16x4 hv0, hv1; \
    _Pragma("unroll") \
    for (int r = 0; r < 4; ++r){ \
      float rg = __builtin_amdgcn_rcpf(1.f + __builtin_amdgcn_exp2f(-LOG2E*((float)g0[r] + a00[r]))); \
      float zg = __builtin_amdgcn_rcpf(1.f + __builtin_amdgcn_exp2f(-LOG2E*((float)g1[r] + a10[r]))); \
      float hn = a20[r] + (float)bn[0][r]; \
      float aa = (float)g2[r] + rg*hn; \
      float ng = 2.f*__builtin_amdgcn_rcpf(1.f + __builtin_amdgcn_exp2f(-2.f*LOG2E*aa)) - 1.f; \
      float h  = ng + zg*((float)ho0[r] - ng); \
      hv0[r] = (f16)h; \
    } \
    _Pragma("unroll") \
    for (int r = 0; r < 4; ++r){ \
      float rg = __builtin_amdgcn_rcpf(1.f + __builtin_amdgcn_exp2f(-LOG2E*((float)g0[4+r] + a01[r]))); \
      float zg = __builtin_amdgcn_rcpf(1.f + __builtin_amdgcn_exp2f(-LOG2E*((float)g1[4+r] + a11[r]))); \
      float hn = a21[r] + (float)bn[1][r]; \
      float aa = (float)g2[4+r] + rg*hn; \
      float ng = 2.f*__builtin_amdgcn_rcpf(1.f + __builtin_amdgcn_exp2f(-2.f*LOG2E*aa)) - 1.f; \
      float h  = ng + zg*((float)ho1[r] - ng); \
      hv1[r] = (f16)h; \
    } \
    *(f16x4*)(sm + ((P)^1)*8192 + hw0) = hv0; \
    *(f16x4*)(sm + ((P)^1)*8192 + hw1) = hv1; \
    if (bval){ \
      *(f16x4*)(hp)      = hv0; \
      *(f16x4*)(hp + 16) = hv1; \
    } \
    hp += (size_t)NB*HD; \
    asm volatile("s_waitcnt lgkmcnt(0)" ::: "memory"); \
    __builtin_amdgcn_sched_barrier(0); \
    __builtin_amdgcn_s_barrier(); \
    __builtin_amdgcn_sched_barrier(0); \
  } while(0)

  for (int th = 0; th < SEQ/2; ++th){
    GRUSTEP(0);
    GRUSTEP(1);
  }
#undef GRUSTEP
#undef DMA_GI
}

// ---------------- LayerNorm(hidden) + ReLU, in place on fp16 [rows][256] -----
// Vectorized: each 64-lane wave handles 2 rows; lane reads f16x8.
__global__ __launch_bounds__(256)
void ln_relu(f16* __restrict__ hs, const float* __restrict__ lnw,
             const float* __restrict__ lnb)
{
  const int tid = threadIdx.x;
  const int wv = tid >> 6;           // 4 waves/block
  const int lane = tid & 63;
  const int half = lane >> 5;        // row within pair
  const int c0 = (lane & 31) * 8;
  float gw[8], gb[8];
  #pragma unroll
  for (int r = 0; r < 8; ++r){ gw[r] = lnw[c0 + r]; gb[r] = lnb[c0 + r]; }
  const int npairs = SEQ * NB / 2;   // 51200
  for (int pair = blockIdx.x * 4 + wv; pair < npairs; pair += gridDim.x * 4){
    f16* p = hs + (size_t)(pair*2 + half) * HD + c0;
    f16x8 v = *(const f16x8*)p;
    float f[8], s = 0.f, q = 0.f;
    #pragma unroll
    for (int r = 0; r < 8; ++r){ f[r] = (float)v[r]; s += f[r]; q += f[r]*f[r]; }
    #pragma unroll
    for (int off = 16; off; off >>= 1){
      s += __shfl_xor(s, off);
      q += __shfl_xor(q, off);
    }
    float mu = s * (1.f / HD);
    float var = q * (1.f / HD) - mu * mu;
    float rs = rsqrtf(var + 1e-5f);
    f16x8 o;
    #pragma unroll
    for (int r = 0; r < 8; ++r){
      float y = (f[r] - mu) * rs * gw[r] + gb[r];
      o[r] = (f16)fmaxf(y, 0.f);
    }
    *(f16x8*)p = o;
  }
}

// ---------------- BatchNorm over axis0 (batch stats) + ReLU ------------------
__global__ __launch_bounds__(512)
void bn_relu(const float* __restrict__ part, const float* __restrict__ g,
             const float* __restrict__ b, float* __restrict__ z)
{
  __shared__ float lds[16];
  const int o = blockIdx.x, s = threadIdx.x, w = s >> 6;
  float y = 0.f;
  #pragma unroll
  for (int p = 0; p < 8; ++p) y += part[((size_t)p * 512 + o) * 512 + s];
  float su = y, q = y * y;
  #pragma unroll
  for (int off = 32; off; off >>= 1){
    su += __shfl_down(su, off);
    q  += __shfl_down(q, off);
  }
  if ((s & 63) == 0){ lds[w] = su; lds[8 + w] = q; }
  __syncthreads();
  float S = 0.f, Q = 0.f;
  #pragma unroll
  for (int i = 0; i < 8; ++i){ S += lds[i]; Q += lds[8 + i]; }
  float mu = S * (1.f / 512.f);
  float var = Q * (1.f / 512.f) - mu * mu;
  float zz = fmaxf((y - mu) * rsqrtf(var + 1e-5f) * g[o] + b[o], 0.f);
  z[(size_t)o * 512 + s] = zz;   // stored transposed [o][s]
}

// ---------------- fc3: out[s][c] = sum_o z[o][s]*w[c][o] + b[c] --------------
__global__ __launch_bounds__(256)
void fc3_k(const float* __restrict__ z, const float* __restrict__ w,
           const float* __restrict__ b, float* __restrict__ out)
{
  __shared__ float lds[12];
  const int s = blockIdx.x, tid = threadIdx.x, wv = tid >> 6;
  float a0 = 0.f, a1 = 0.f, a2 = 0.f;
  for (int o = tid; o < 512; o += 256){
    float zz = z[(size_t)o * 512 + s];
    a0 += zz * w[o];
    a1 += zz * w[512 + o];
    a2 += zz * w[1024 + o];
  }
  #pragma unroll
  for (int off = 32; off; off >>= 1){
    a0 += __shfl_down(a0, off);
    a1 += __shfl_down(a1, off);
    a2 += __shfl_down(a2, off);
  }
  if ((tid & 63) == 0){ lds[wv] = a0; lds[4 + wv] = a1; lds[8 + wv] = a2; }
  __syncthreads();
  if (tid == 0){
    out[s*3 + 0] = lds[0] + lds[1] + lds[2]  + lds[3]  + b[0];
    out[s*3 + 1] = lds[4] + lds[5] + lds[6]  + lds[7]  + b[1];
    out[s*3 + 2] = lds[8] + lds[9] + lds[10] + lds[11] + b[2];
  }
}

extern "C" void kernel_launch(void* const* d_in, const int* in_sizes, int n_in,
                              void* d_out, int out_size, void* d_ws, size_t ws_size,
                              hipStream_t stream)
{
  (void)in_sizes; (void)n_in; (void)out_size; (void)ws_size;
  const float* x    = (const float*)d_in[0];
  const float* wih0 = (const float*)d_in[1];
  const float* whh0 = (const float*)d_in[2];
  const float* bih0 = (const float*)d_in[3];
  const float* bhh0 = (const float*)d_in[4];
  const float* wih1 = (const float*)d_in[5];
  const float* whh1 = (const float*)d_in[6];
  const float* bih1 = (const float*)d_in[7];
  const float* bhh1 = (const float*)d_in[8];
  const float* lnw  = (const float*)d_in[9];
  const float* lnb  = (const float*)d_in[10];
  const float* fc2w = (const float*)d_in[11];
  // d_in[12] = fc2_b skipped: BN mean-centering cancels constant column bias.
  const float* bng  = (const float*)d_in[13];
  const float* bnb  = (const float*)d_in[14];
  const float* fc3w = (const float*)d_in[15];
  const float* fc3b = (const float*)d_in[16];
  float* out = (float*)d_out;

  char* ws = (char*)d_ws;
  size_t off = 0;
  auto alloc = [&](size_t bytes) -> void* {
    void* p = ws + off; off += (bytes + 255) & ~(size_t)255; return p;
  };
  f16* GI     = (f16*)alloc((size_t)SEQ*GI_TSTRIDE*2);  // 163.6 MB (permuted layout)
  f16* X16    = (f16*)alloc((size_t)SEQ*NB*64*2);       // 13.1 MB
  f16* WI0    = (f16*)alloc((size_t)768*64*2);
  f16* WH0    = (f16*)alloc((size_t)768*256*2);
  f16* WI1    = (f16*)alloc((size_t)768*256*2);
  f16* WH1    = (f16*)alloc((size_t)768*256*2);
  f16* HS0    = (f16*)alloc((size_t)SEQ*NB*256*2);      // 52.4 MB
  f16* HS1    = (f16*)alloc((size_t)SEQ*NB*256*2);      // 52.4 MB
  float* PART = (float*)alloc((size_t)8*512*512*4);     // 8.4 MB
  float* Z    = (float*)alloc((size_t)512*512*4);       // 1 MB (total ~292 MB)
  f16* FC2W   = GI;   // aliased: GI dead after gru1, FC2W converted after gru1

  cvt_f32_f16<<<2048,256,0,stream>>>(x,    X16,  SEQ*NB*64/4);
  cvt_f32_f16<<<64,  256,0,stream>>>(wih0, WI0,  768*64/4);
  cvt_f32_f16<<<192, 256,0,stream>>>(whh0, WH0,  768*256/4);
  cvt_f32_f16<<<192, 256,0,stream>>>(wih1, WI1,  768*256/4);
  cvt_f32_f16<<<192, 256,0,stream>>>(whh1, WH1,  768*256/4);

  dim3 g0(800, 6, 1);
  // gi0 = x @ w_ih0^T + b_ih0 (+ b_hh0 for r,z gates), permuted layout
  gemm_bt<0><<<g0, 256, 0, stream>>>(X16, WI0, GI, nullptr, bih0, bhh0, 64, GD, 64);
  gru_layer<<<NBLK, 512, 0, stream>>>(WH0, bhh0, GI, HS0);
  gemm_bt<0><<<g0, 256, 0, stream>>>(HS0, WI1, GI, nullptr, bih1, bhh1, 256, GD, 256);
  gru_layer<<<NBLK, 512, 0, stream>>>(WH1, bhh1, GI, HS1);
  // LayerNorm + ReLU in place -> hflat (fp16, layout already (512, 51200))
  ln_relu<<<3200, 256, 0, stream>>>(HS1, lnw, lnb);
  // fc2 weights converted now (GI dead), into GI-aliased buffer
  cvt_f32_f16<<<4096,256,0,stream>>>(fc2w, FC2W, 512*51200/4);
  dim3 g2(4, 4, 8);
  gemm_bt<1><<<g2, 256, 0, stream>>>(FC2W, HS1, nullptr, PART, nullptr, nullptr, 51200, 512, 6400);
  bn_relu<<<512, 512, 0, stream>>>(PART, bng, bnb, Z);
  fc3_k<<<512, 256, 0, stream>>>(Z, fc3w, fc3b, out);
}